// Round 6
// baseline (267.063 us; speedup 1.0000x reference)
//
#include <hip/hip_runtime.h>
#include <hip/hip_bf16.h>

#define N 16384
#define D 128
#define RS 16                        // row splits
#define CTILES 32                    // col tiles of 512 (8 waves x 64 cols)
#define ROWS_PER_SPLIT (N / RS)      // 1024
#define NSTAGE (ROWS_PER_SPLIT / 64) // 16 stages of 64 rows

typedef __attribute__((ext_vector_type(8))) short bf16x8;
typedef __attribute__((ext_vector_type(4))) float f32x4;

#define GLOBAL_AS __attribute__((address_space(1)))
#define LDS_AS __attribute__((address_space(3)))

// ---------------- Kernel A: normalize targets -> bf16 bn ----------------
__global__ __launch_bounds__(256) void knorm(const float* __restrict__ t,
                                             __hip_bfloat16* __restrict__ bn) {
    const int row  = blockIdx.x * 4 + (threadIdx.x >> 6);
    const int lane = threadIdx.x & 63;
    const float2 v = *(const float2*)(t + (size_t)row * D + lane * 2);
    float ss = v.x * v.x + v.y * v.y;
#pragma unroll
    for (int m = 1; m <= 32; m <<= 1) ss += __shfl_xor(ss, m, 64);
    const float inv = rsqrtf(ss);
    __hip_bfloat162 o;
    o.x = __float2bfloat16(v.x * inv);
    o.y = __float2bfloat16(v.y * inv);
    *(__hip_bfloat162*)(bn + (size_t)row * D + lane * 2) = o;
}

// ---------------- Kernel B: fused bn @ bn^T + per-column group-argmax ----------------
// 512 blocks x 8 waves (512 thr). Wave w: cols [ct*512 + w*64, +64) persistent in
// fb[4][4] (64 regs). Rows [s*1024,(s+1)*1024) staged once per block into a
// double-buffered 2x16KB LDS tile (64 rows/stage), counted vmcnt(2) (never 0).
// Per-wave regs ~120 -> 4 waves/SIMD, 2 blocks/CU, grid fully resident.
__global__ __launch_bounds__(512, 4) void kargmax(const __hip_bfloat16* __restrict__ bn,
                                                  float* __restrict__ pval,
                                                  int* __restrict__ pcode) {
    __shared__ __align__(16) char lds[2 * 16384];

    const int tid  = threadIdx.x;
    const int lane = tid & 63;
    const int w    = tid >> 6;                 // 0..7
    const int b    = blockIdx.x;
    const int ct   = b & (CTILES - 1);
    const int s    = b >> 5;
    const int j0w  = ct * 512 + w * 64;
    const int rbase = s * ROWS_PER_SPLIT;

    const int lr = lane & 15;
    const int lk = lane >> 4;

    // persistent B fragments: 64 cols x 128 K (64 VGPRs)
    bf16x8 fb[4][4];
#pragma unroll
    for (int cs = 0; cs < 4; ++cs)
#pragma unroll
        for (int ks = 0; ks < 4; ++ks)
            fb[cs][ks] = *(const bf16x8*)(bn + (size_t)(j0w + cs * 16 + lr) * D + ks * 32 + lk * 8);

    const char* bnb = (const char*)bn;

    float mv[4];
#pragma unroll
    for (int cs = 0; cs < 4; ++cs) mv[cs] = -1e30f;

    // stage t: rows rbase+t*64 .. +63 -> buffer (t&1). Source pre-swizzled
    // (cb ^ row&7) so LDS dest stays linear; ds_read applies the same XOR.
#define STAGE(t_) do {                                                          \
    const int r0s_ = rbase + (t_) * 64;                                         \
    char* dst_ = lds + ((t_) & 1) * 16384;                                      \
    _Pragma("unroll")                                                           \
    for (int u_ = 0; u_ < 2; ++u_) {                                            \
        const int chunk_ = u_ * 512 + tid;                                      \
        const int row_   = chunk_ >> 4;                                         \
        const int cb_    = (chunk_ & 15) ^ (row_ & 7);                          \
        __builtin_amdgcn_global_load_lds(                                       \
            (const GLOBAL_AS void*)(bnb + (size_t)(r0s_ + row_) * 256 + cb_ * 16), \
            (LDS_AS void*)(dst_ + chunk_ * 16), 16, 0, 0);                      \
    } } while (0)

    STAGE(0);
    STAGE(1);

    for (int t = 0; t < NSTAGE; ++t) {
        // stage t's 2 loads (oldest) done; stage t+1's 2 stay in flight
        asm volatile("s_waitcnt vmcnt(2)" ::: "memory");
        __builtin_amdgcn_s_barrier();
        const char* cbase = lds + (t & 1) * 16384;
#pragma unroll
        for (int si = 0; si < 4; ++si) {
            bf16x8 fa[4];
#pragma unroll
            for (int ks = 0; ks < 4; ++ks)
                fa[ks] = *(const bf16x8*)(cbase + (si * 16 + lr) * 256 +
                                          (((ks * 4 + lk) ^ (lr & 7)) * 16));
            f32x4 acc[4];
#pragma unroll
            for (int cs = 0; cs < 4; ++cs) {
                acc[cs] = __builtin_amdgcn_mfma_f32_16x16x32_bf16(
                    fa[0], fb[cs][0], (f32x4){0.f, 0.f, 0.f, 0.f}, 0, 0, 0);
#pragma unroll
                for (int ks = 1; ks < 4; ++ks)
                    acc[cs] = __builtin_amdgcn_mfma_f32_16x16x32_bf16(
                        fa[ks], fb[cs][ks], acc[cs], 0, 0, 0);
            }
            const int itg = t * 4 + si;
            const int r0_ = rbase + itg * 16;
            if ((unsigned)(r0_ - j0w) < 64u) {           // wave-uniform diag fixup
#pragma unroll
                for (int cs = 0; cs < 4; ++cs)
                    if (r0_ == j0w + cs * 16) {
#pragma unroll
                        for (int r = 0; r < 4; ++r)
                            acc[cs][r] = (lk * 4 + r == lr) ? acc[cs][r] - 1.0f : acc[cs][r];
                    }
            }
            const unsigned gid = (unsigned)(itg * 4 + lk);   // 4-row group id, 0..255
#pragma unroll
            for (int cs = 0; cs < 4; ++cs) {
                const float g_ = fmaxf(fmaxf(acc[cs][0], acc[cs][1]),
                                       fmaxf(acc[cs][2], acc[cs][3]));
                const unsigned gb_ = (__float_as_uint(g_) & 0xFFFFFF00u) | gid;
                mv[cs] = fmaxf(mv[cs], __uint_as_float(gb_));
            }
        }
        __builtin_amdgcn_s_barrier();   // all waves done reading buf (t&1)
        STAGE(t + 2);                   // t>=14 overshoots into pval pad — allocated, unused
    }
#undef STAGE

    // reduce across the 4 lk groups (packed fmax — group id rides in low byte);
    // each wave owns its 64 cols: no inter-wave merge needed.
#pragma unroll
    for (int cs = 0; cs < 4; ++cs) {
        float v = mv[cs];
        v = fmaxf(v, __shfl_xor(v, 16, 64));
        v = fmaxf(v, __shfl_xor(v, 32, 64));
        if (lane < 16) {
            pval[(size_t)s * N + j0w + cs * 16 + lr]  = v;
            pcode[(size_t)s * N + j0w + cs * 16 + lr] =
                rbase + (int)(__float_as_uint(v) & 255u) * 4;
        }
    }
}

// ---------------- Kernel C: merge splits, re-rank 4 candidates in fp32, hinge ----------------
__global__ __launch_bounds__(256) void kloss(const float* __restrict__ q,
                                             const float* __restrict__ t,
                                             const float* __restrict__ pval,
                                             const int* __restrict__ pcode,
                                             float* __restrict__ bsum) {
    const int j    = blockIdx.x * 4 + (threadIdx.x >> 6);
    const int lane = threadIdx.x & 63;

    // merge the RS split winners (lane s holds split s)
    float v = -1e30f;
    int   c = 0;
    if (lane < RS) { v = pval[(size_t)lane * N + j]; c = pcode[(size_t)lane * N + j]; }
#pragma unroll
    for (int m = 1; m <= 8; m <<= 1) {
        const float ov = __shfl_xor(v, m, 64);
        const int   oc = __shfl_xor(c, m, 64);
        if (ov > v || (ov == v && oc < c)) { v = ov; c = oc; }
    }
    c = __shfl(c, 0, 64);

    const float2 qv = *(const float2*)(q + (size_t)j * D + lane * 2);
    const float2 tv = *(const float2*)(t + (size_t)j * D + lane * 2);
    float qq = qv.x * qv.x + qv.y * qv.y;
    float tt = tv.x * tv.x + tv.y * tv.y;
    float qt = qv.x * tv.x + qv.y * tv.y;
    float ww[4], wt[4], qw[4];
#pragma unroll
    for (int r = 0; r < 4; ++r) {
        const float2 wv = *(const float2*)(t + (size_t)(c + r) * D + lane * 2);
        ww[r] = wv.x * wv.x + wv.y * wv.y;
        wt[r] = wv.x * tv.x + wv.y * tv.y;
        qw[r] = wv.x * qv.x + wv.y * qv.y;
    }
#pragma unroll
    for (int m = 1; m <= 32; m <<= 1) {
        qq += __shfl_xor(qq, m, 64);
        tt += __shfl_xor(tt, m, 64);
        qt += __shfl_xor(qt, m, 64);
#pragma unroll
        for (int r = 0; r < 4; ++r) {
            ww[r] += __shfl_xor(ww[r], m, 64);
            wt[r] += __shfl_xor(wt[r], m, 64);
            qw[r] += __shfl_xor(qw[r], m, 64);
        }
    }
    const float pos = qt * rsqrtf(qq * tt);
    float best = -1e30f, neg = 0.f;
#pragma unroll
    for (int r = 0; r < 4; ++r) {
        float cr = wt[r] * rsqrtf(ww[r] * tt);
        if (c + r == j) cr -= 1.0f;              // diag candidate, matches sim - eye
        if (cr > best) { best = cr; neg = qw[r] * rsqrtf(qq * ww[r]); }
    }
    const float l = fmaxf(0.f, 1.0f - pos + neg);

    __shared__ float ls[4];
    if (lane == 0) ls[threadIdx.x >> 6] = l;
    __syncthreads();
    if (threadIdx.x == 0) bsum[blockIdx.x] = ls[0] + ls[1] + ls[2] + ls[3];
}

// ---------------- Kernel D: deterministic final mean ----------------
__global__ __launch_bounds__(256) void kfinal(const float* __restrict__ bsum,
                                              float* __restrict__ out) {
    float sum = 0.f;
    for (int i = threadIdx.x; i < N / 4; i += 256) sum += bsum[i];
#pragma unroll
    for (int m = 1; m <= 32; m <<= 1) sum += __shfl_xor(sum, m, 64);
    __shared__ float ws2[4];
    if ((threadIdx.x & 63) == 0) ws2[threadIdx.x >> 6] = sum;
    __syncthreads();
    if (threadIdx.x == 0) out[0] = (ws2[0] + ws2[1] + ws2[2] + ws2[3]) * (1.0f / N);
}

extern "C" void kernel_launch(void* const* d_in, const int* in_sizes, int n_in,
                              void* d_out, int out_size, void* d_ws, size_t ws_size,
                              hipStream_t stream) {
    const float* q = (const float*)d_in[0];
    const float* t = (const float*)d_in[1];
    char* ws = (char*)d_ws;

    __hip_bfloat16* bn = (__hip_bfloat16*)ws;                          // 4 MB (must stay first)
    float* pval = (float*)(ws + (size_t)N * D * 2);                    // 1 MB (also overshoot pad)
    int*   pcode = (int*)(ws + (size_t)N * D * 2 + (size_t)RS * N * 4);// 1 MB
    float* bsum = (float*)(ws + (size_t)N * D * 2 + (size_t)2 * RS * N * 4); // 16 KB

    knorm<<<dim3(N / 4), dim3(256), 0, stream>>>(t, bn);
    kargmax<<<dim3(CTILES * RS), dim3(512), 0, stream>>>(bn, pval, pcode);
    kloss<<<dim3(N / 4), dim3(256), 0, stream>>>(q, t, pval, pcode, bsum);
    kfinal<<<dim3(1), dim3(256), 0, stream>>>(bsum, (float*)d_out);
}

// Round 7
// 260.945 us; speedup vs baseline: 1.0234x; 1.0234x over previous
//
#include <hip/hip_runtime.h>
#include <hip/hip_bf16.h>

#define N 16384
#define D 128
#define RS 16                        // row splits
#define CTILES 32                    // col tiles of 512 (8 waves x 64 cols)
#define ROWS_PER_SPLIT (N / RS)      // 1024
#define NSTAGE (ROWS_PER_SPLIT / 64) // 16 stages of 64 rows

typedef __attribute__((ext_vector_type(8))) short bf16x8;
typedef __attribute__((ext_vector_type(4))) float f32x4;

#define GLOBAL_AS __attribute__((address_space(1)))
#define LDS_AS __attribute__((address_space(3)))

// ---------------- Kernel A: normalize targets -> bf16 bn ----------------
__global__ __launch_bounds__(256) void knorm(const float* __restrict__ t,
                                             __hip_bfloat16* __restrict__ bn) {
    const int row  = blockIdx.x * 4 + (threadIdx.x >> 6);
    const int lane = threadIdx.x & 63;
    const float2 v = *(const float2*)(t + (size_t)row * D + lane * 2);
    float ss = v.x * v.x + v.y * v.y;
#pragma unroll
    for (int m = 1; m <= 32; m <<= 1) ss += __shfl_xor(ss, m, 64);
    const float inv = rsqrtf(ss);
    __hip_bfloat162 o;
    o.x = __float2bfloat16(v.x * inv);
    o.y = __float2bfloat16(v.y * inv);
    *(__hip_bfloat162*)(bn + (size_t)row * D + lane * 2) = o;
}

// ---------------- Kernel B: fused bn @ bn^T + per-column group-argmax ----------------
// 512 blocks x 8 waves. Wave w: cols [ct*512 + w*64, +64) persistent in fb[4][4].
// Rows [s*1024,(s+1)*1024) staged per-block into triple-buffered 3x16KB LDS,
// counted vmcnt(2), ONE raw barrier per stage. XCD-bijective decode: XCD x gets
// 8 ct x 8 s -> 3 MB hot set < 4 MB L2 (the R6 regression was losing this).
__global__ __launch_bounds__(512, 4) void kargmax(const __hip_bfloat16* __restrict__ bn,
                                                  float* __restrict__ pval,
                                                  int* __restrict__ pcode) {
    __shared__ __align__(16) char lds[3 * 16384];

    const int tid  = threadIdx.x;
    const int lane = tid & 63;
    const int w    = tid >> 6;                 // 0..7
    const int b    = blockIdx.x;
    const int x    = b & 7;                    // XCD id (round-robin dispatch)
    const int i    = b >> 3;                   // 0..63 within XCD
    const int ct   = (x >> 1) * 8 + (i & 7);   // 8 col-tiles per XCD
    const int s    = (x & 1) * 8 + (i >> 3);   // 8 splits per XCD
    const int j0w  = ct * 512 + w * 64;
    const int rbase = s * ROWS_PER_SPLIT;

    const int lr = lane & 15;
    const int lk = lane >> 4;

    // persistent B fragments: 64 cols x 128 K (64 VGPRs)
    bf16x8 fb[4][4];
#pragma unroll
    for (int cs = 0; cs < 4; ++cs)
#pragma unroll
        for (int ks = 0; ks < 4; ++ks)
            fb[cs][ks] = *(const bf16x8*)(bn + (size_t)(j0w + cs * 16 + lr) * D + ks * 32 + lk * 8);

    const char* bnb = (const char*)bn;

    float mv[4];
#pragma unroll
    for (int cs = 0; cs < 4; ++cs) mv[cs] = -1e30f;

    // stage t: rows rbase+t*64 .. +63 -> buffer (t%3). Source pre-swizzled
    // (cb ^ row&7) so LDS dest stays linear; ds_read applies the same XOR.
#define STAGE(t_) do {                                                          \
    const int r0s_ = rbase + (t_) * 64;                                         \
    char* dst_ = lds + ((t_) % 3) * 16384;                                      \
    _Pragma("unroll")                                                           \
    for (int u_ = 0; u_ < 2; ++u_) {                                            \
        const int chunk_ = u_ * 512 + tid;                                      \
        const int row_   = chunk_ >> 4;                                         \
        const int cb_    = (chunk_ & 15) ^ (row_ & 7);                          \
        __builtin_amdgcn_global_load_lds(                                       \
            (const GLOBAL_AS void*)(bnb + (size_t)(r0s_ + row_) * 256 + cb_ * 16), \
            (LDS_AS void*)(dst_ + chunk_ * 16), 16, 0, 0);                      \
    } } while (0)

    STAGE(0);
    STAGE(1);

    for (int t = 0; t < NSTAGE; ++t) {
        // oldest 2 loads (stage t) landed; stage t+1's 2 stay in flight
        asm volatile("s_waitcnt vmcnt(2)" ::: "memory");
        __builtin_amdgcn_s_barrier();   // all waves' stage-t loads landed; buf (t+2)%3 free
        STAGE(t + 2);                   // t>=14 overshoots into pval pad — allocated, unused
        const char* cbase = lds + (t % 3) * 16384;
        const char* r0p = cbase + lr * 256;
        const int e0 = (lk ^ (lr & 7)) << 4;
        const int e1 = e0 ^ 64;
#pragma unroll
        for (int si = 0; si < 4; ++si) {
            bf16x8 fa[4];
            fa[0] = *(const bf16x8*)(r0p + si * 4096 + e0);
            fa[1] = *(const bf16x8*)(r0p + si * 4096 + e1);
            fa[2] = *(const bf16x8*)(r0p + si * 4096 + e0 + 128);
            fa[3] = *(const bf16x8*)(r0p + si * 4096 + e1 + 128);
            f32x4 acc[4];
            __builtin_amdgcn_s_setprio(1);
#pragma unroll
            for (int cs = 0; cs < 4; ++cs) {
                acc[cs] = __builtin_amdgcn_mfma_f32_16x16x32_bf16(
                    fa[0], fb[cs][0], (f32x4){0.f, 0.f, 0.f, 0.f}, 0, 0, 0);
#pragma unroll
                for (int ks = 1; ks < 4; ++ks)
                    acc[cs] = __builtin_amdgcn_mfma_f32_16x16x32_bf16(
                        fa[ks], fb[cs][ks], acc[cs], 0, 0, 0);
            }
            __builtin_amdgcn_s_setprio(0);
            const int itg = t * 4 + si;
            const int r0_ = rbase + itg * 16;
            if ((unsigned)(r0_ - j0w) < 64u) {           // wave-uniform diag fixup
#pragma unroll
                for (int cs = 0; cs < 4; ++cs)
                    if (r0_ == j0w + cs * 16) {
#pragma unroll
                        for (int r = 0; r < 4; ++r)
                            acc[cs][r] = (lk * 4 + r == lr) ? acc[cs][r] - 1.0f : acc[cs][r];
                    }
            }
            const unsigned gid = (unsigned)(itg * 4 + lk);   // 4-row group id, 0..255
#pragma unroll
            for (int cs = 0; cs < 4; ++cs) {
                const float g_ = fmaxf(fmaxf(fmaxf(acc[cs][0], acc[cs][1]),
                                             acc[cs][2]), acc[cs][3]);   // max3 + max
                const unsigned gb_ = (__float_as_uint(g_) & 0xFFFFFF00u) | gid;
                mv[cs] = fmaxf(mv[cs], __uint_as_float(gb_));
            }
        }
    }
#undef STAGE

    // reduce across the 4 lk groups (packed fmax — group id rides in low byte);
    // each wave owns its 64 cols: no inter-wave merge needed.
#pragma unroll
    for (int cs = 0; cs < 4; ++cs) {
        float v = mv[cs];
        v = fmaxf(v, __shfl_xor(v, 16, 64));
        v = fmaxf(v, __shfl_xor(v, 32, 64));
        if (lane < 16) {
            pval[(size_t)s * N + j0w + cs * 16 + lr]  = v;
            pcode[(size_t)s * N + j0w + cs * 16 + lr] =
                rbase + (int)(__float_as_uint(v) & 255u) * 4;
        }
    }
}

// ---------------- Kernel C: merge splits, re-rank 4 candidates in fp32, hinge ----------------
__global__ __launch_bounds__(256) void kloss(const float* __restrict__ q,
                                             const float* __restrict__ t,
                                             const float* __restrict__ pval,
                                             const int* __restrict__ pcode,
                                             float* __restrict__ bsum) {
    const int j    = blockIdx.x * 4 + (threadIdx.x >> 6);
    const int lane = threadIdx.x & 63;

    // merge the RS split winners (lane s holds split s)
    float v = -1e30f;
    int   c = 0;
    if (lane < RS) { v = pval[(size_t)lane * N + j]; c = pcode[(size_t)lane * N + j]; }
#pragma unroll
    for (int m = 1; m <= 8; m <<= 1) {
        const float ov = __shfl_xor(v, m, 64);
        const int   oc = __shfl_xor(c, m, 64);
        if (ov > v || (ov == v && oc < c)) { v = ov; c = oc; }
    }
    c = __shfl(c, 0, 64);

    const float2 qv = *(const float2*)(q + (size_t)j * D + lane * 2);
    const float2 tv = *(const float2*)(t + (size_t)j * D + lane * 2);
    float qq = qv.x * qv.x + qv.y * qv.y;
    float tt = tv.x * tv.x + tv.y * tv.y;
    float qt = qv.x * tv.x + qv.y * tv.y;
    float ww[4], wt[4], qw[4];
#pragma unroll
    for (int r = 0; r < 4; ++r) {
        const float2 wv = *(const float2*)(t + (size_t)(c + r) * D + lane * 2);
        ww[r] = wv.x * wv.x + wv.y * wv.y;
        wt[r] = wv.x * tv.x + wv.y * tv.y;
        qw[r] = wv.x * qv.x + wv.y * qv.y;
    }
#pragma unroll
    for (int m = 1; m <= 32; m <<= 1) {
        qq += __shfl_xor(qq, m, 64);
        tt += __shfl_xor(tt, m, 64);
        qt += __shfl_xor(qt, m, 64);
#pragma unroll
        for (int r = 0; r < 4; ++r) {
            ww[r] += __shfl_xor(ww[r], m, 64);
            wt[r] += __shfl_xor(wt[r], m, 64);
            qw[r] += __shfl_xor(qw[r], m, 64);
        }
    }
    const float pos = qt * rsqrtf(qq * tt);
    float best = -1e30f, neg = 0.f;
#pragma unroll
    for (int r = 0; r < 4; ++r) {
        float cr = wt[r] * rsqrtf(ww[r] * tt);
        if (c + r == j) cr -= 1.0f;              // diag candidate, matches sim - eye
        if (cr > best) { best = cr; neg = qw[r] * rsqrtf(qq * ww[r]); }
    }
    const float l = fmaxf(0.f, 1.0f - pos + neg);

    __shared__ float ls[4];
    if (lane == 0) ls[threadIdx.x >> 6] = l;
    __syncthreads();
    if (threadIdx.x == 0) bsum[blockIdx.x] = ls[0] + ls[1] + ls[2] + ls[3];
}

// ---------------- Kernel D: deterministic final mean ----------------
__global__ __launch_bounds__(256) void kfinal(const float* __restrict__ bsum,
                                              float* __restrict__ out) {
    float sum = 0.f;
    for (int i = threadIdx.x; i < N / 4; i += 256) sum += bsum[i];
#pragma unroll
    for (int m = 1; m <= 32; m <<= 1) sum += __shfl_xor(sum, m, 64);
    __shared__ float ws2[4];
    if ((threadIdx.x & 63) == 0) ws2[threadIdx.x >> 6] = sum;
    __syncthreads();
    if (threadIdx.x == 0) out[0] = (ws2[0] + ws2[1] + ws2[2] + ws2[3]) * (1.0f / N);
}

extern "C" void kernel_launch(void* const* d_in, const int* in_sizes, int n_in,
                              void* d_out, int out_size, void* d_ws, size_t ws_size,
                              hipStream_t stream) {
    const float* q = (const float*)d_in[0];
    const float* t = (const float*)d_in[1];
    char* ws = (char*)d_ws;

    __hip_bfloat16* bn = (__hip_bfloat16*)ws;                          // 4 MB (must stay first)
    float* pval = (float*)(ws + (size_t)N * D * 2);                    // 1 MB (also overshoot pad)
    int*   pcode = (int*)(ws + (size_t)N * D * 2 + (size_t)RS * N * 4);// 1 MB
    float* bsum = (float*)(ws + (size_t)N * D * 2 + (size_t)2 * RS * N * 4); // 16 KB

    knorm<<<dim3(N / 4), dim3(256), 0, stream>>>(t, bn);
    kargmax<<<dim3(CTILES * RS), dim3(512), 0, stream>>>(bn, pval, pcode);
    kloss<<<dim3(N / 4), dim3(256), 0, stream>>>(q, t, pval, pcode, bsum);
    kfinal<<<dim3(1), dim3(256), 0, stream>>>(bsum, (float*)d_out);
}

// Round 8
// 248.626 us; speedup vs baseline: 1.0742x; 1.0496x over previous
//
#include <hip/hip_runtime.h>
#include <hip/hip_bf16.h>

#define N 16384
#define D 128
#define RS 16                        // row splits (1024 rows each)
#define CTILES 16                    // col tiles of 1024 (16 waves x 64 cols)
#define ROWS_PER_SPLIT (N / RS)      // 1024
#define NSTAGE (ROWS_PER_SPLIT / 64) // 16 stages of 64 rows

typedef __attribute__((ext_vector_type(8))) short bf16x8;
typedef __attribute__((ext_vector_type(4))) float f32x4;

#define GLOBAL_AS __attribute__((address_space(1)))
#define LDS_AS __attribute__((address_space(3)))

// ---------------- Kernel A: normalize targets -> bf16 bn ----------------
__global__ __launch_bounds__(256) void knorm(const float* __restrict__ t,
                                             __hip_bfloat16* __restrict__ bn) {
    const int row  = blockIdx.x * 4 + (threadIdx.x >> 6);
    const int lane = threadIdx.x & 63;
    const float2 v = *(const float2*)(t + (size_t)row * D + lane * 2);
    float ss = v.x * v.x + v.y * v.y;
#pragma unroll
    for (int m = 1; m <= 32; m <<= 1) ss += __shfl_xor(ss, m, 64);
    const float inv = rsqrtf(ss);
    __hip_bfloat162 o;
    o.x = __float2bfloat16(v.x * inv);
    o.y = __float2bfloat16(v.y * inv);
    *(__hip_bfloat162*)(bn + (size_t)row * D + lane * 2) = o;
}

// ---------------- Kernel B: fused bn @ bn^T + per-column group-argmax ----------------
// 256 blocks (1/CU) x 16 waves (1024 thr). Wave w: cols [ct*1024 + w*64, +64)
// persistent in fb[4][4] (64 VGPR). Rows [s*1024,(s+1)*1024) staged per-block into
// triple-buffered 3x16KB LDS (64 rows/stage, ONE global_load_lds per thread per
// stage), counted vmcnt(1), one barrier per stage. BN=1024 halves logical A-fetch
// vs BN=512; XCD decode (4 ct x 8 s per XCD) keeps the per-XCD hot set at 3 MB.
__global__ __launch_bounds__(1024, 4) void kargmax(const __hip_bfloat16* __restrict__ bn,
                                                   float* __restrict__ pval,
                                                   int* __restrict__ pcode) {
    __shared__ __align__(16) char lds[3 * 16384];

    const int tid  = threadIdx.x;
    const int lane = tid & 63;
    const int w    = tid >> 6;                 // 0..15
    const int b    = blockIdx.x;
    const int x    = b & 7;                    // XCD id (round-robin dispatch)
    const int i    = b >> 3;                   // 0..31 within XCD
    const int ct   = (x >> 1) * 4 + (i & 3);   // 4 col-tiles per XCD
    const int s    = (x & 1) * 8 + (i >> 2);   // 8 splits per XCD
    const int j0w  = ct * 1024 + w * 64;
    const int rbase = s * ROWS_PER_SPLIT;

    const int lr = lane & 15;
    const int lk = lane >> 4;

    // persistent B fragments: 64 cols x 128 K (64 VGPRs)
    bf16x8 fb[4][4];
#pragma unroll
    for (int cs = 0; cs < 4; ++cs)
#pragma unroll
        for (int ks = 0; ks < 4; ++ks)
            fb[cs][ks] = *(const bf16x8*)(bn + (size_t)(j0w + cs * 16 + lr) * D + ks * 32 + lk * 8);

    const char* bnb = (const char*)bn;
    const int srow = tid >> 4;                       // staging row 0..63
    const int scb  = (tid & 15) ^ (srow & 7);        // pre-swizzled source chunk

    float mv[4];
#pragma unroll
    for (int cs = 0; cs < 4; ++cs) mv[cs] = -1e30f;

    // stage t: rows rbase+t*64 .. +63 -> buffer (t%3); 1024 threads x 16B = 16 KB.
#define STAGE(t_) do {                                                              \
    __builtin_amdgcn_global_load_lds(                                               \
        (const GLOBAL_AS void*)(bnb + (size_t)(rbase + (t_) * 64 + srow) * 256 + scb * 16), \
        (LDS_AS void*)(lds + ((t_) % 3) * 16384 + tid * 16), 16, 0, 0);             \
    } while (0)

    STAGE(0);
    STAGE(1);

    for (int t = 0; t < NSTAGE; ++t) {
        // own stage-t load (oldest) landed; stage t+1's stays in flight
        asm volatile("s_waitcnt vmcnt(1)" ::: "memory");
        __builtin_amdgcn_s_barrier();   // all waves' stage-t loads landed; buf (t+2)%3 free
        STAGE(t + 2);                   // overshoot (s=15,t>=14) lands in pval pad — unused
        const char* r0p = lds + (t % 3) * 16384 + lr * 256;
        const int e0 = ((lk ^ (lr & 7)) << 4);
#pragma unroll
        for (int si = 0; si < 4; ++si) {
            bf16x8 fa[4];
            fa[0] = *(const bf16x8*)(r0p + si * 4096 + e0);
            fa[1] = *(const bf16x8*)(r0p + si * 4096 + (e0 ^ 64));
            fa[2] = *(const bf16x8*)(r0p + si * 4096 + (e0 ^ 128));
            fa[3] = *(const bf16x8*)(r0p + si * 4096 + (e0 ^ 192));
            f32x4 acc[4];
            __builtin_amdgcn_s_setprio(1);
#pragma unroll
            for (int cs = 0; cs < 4; ++cs) {
                acc[cs] = __builtin_amdgcn_mfma_f32_16x16x32_bf16(
                    fa[0], fb[cs][0], (f32x4){0.f, 0.f, 0.f, 0.f}, 0, 0, 0);
#pragma unroll
                for (int ks = 1; ks < 4; ++ks)
                    acc[cs] = __builtin_amdgcn_mfma_f32_16x16x32_bf16(
                        fa[ks], fb[cs][ks], acc[cs], 0, 0, 0);
            }
            __builtin_amdgcn_s_setprio(0);
            const int itg = t * 4 + si;
            const int r0_ = rbase + itg * 16;
            if ((unsigned)(r0_ - j0w) < 64u) {           // wave-uniform diag fixup
#pragma unroll
                for (int cs = 0; cs < 4; ++cs)
                    if (r0_ == j0w + cs * 16) {
#pragma unroll
                        for (int r = 0; r < 4; ++r)
                            acc[cs][r] = (lk * 4 + r == lr) ? acc[cs][r] - 1.0f : acc[cs][r];
                    }
            }
            const unsigned gid = (unsigned)(itg * 4 + lk);   // 4-row group id, 0..255
#pragma unroll
            for (int cs = 0; cs < 4; ++cs) {
                const float g_ = fmaxf(fmaxf(fmaxf(acc[cs][0], acc[cs][1]),
                                             acc[cs][2]), acc[cs][3]);
                const unsigned gb_ = (__float_as_uint(g_) & 0xFFFFFF00u) | gid;
                mv[cs] = fmaxf(mv[cs], __uint_as_float(gb_));
            }
        }
    }
#undef STAGE

    // reduce across the 4 lk groups (packed fmax — group id rides in low byte);
    // each wave owns its 64 cols: no inter-wave merge needed.
#pragma unroll
    for (int cs = 0; cs < 4; ++cs) {
        float v = mv[cs];
        v = fmaxf(v, __shfl_xor(v, 16, 64));
        v = fmaxf(v, __shfl_xor(v, 32, 64));
        if (lane < 16) {
            pval[(size_t)s * N + j0w + cs * 16 + lr]  = v;
            pcode[(size_t)s * N + j0w + cs * 16 + lr] =
                rbase + (int)(__float_as_uint(v) & 255u) * 4;
        }
    }
}

// ---------------- Kernel C: merge splits, re-rank 4 candidates in fp32, hinge ----------------
__global__ __launch_bounds__(256) void kloss(const float* __restrict__ q,
                                             const float* __restrict__ t,
                                             const float* __restrict__ pval,
                                             const int* __restrict__ pcode,
                                             float* __restrict__ bsum) {
    const int j    = blockIdx.x * 4 + (threadIdx.x >> 6);
    const int lane = threadIdx.x & 63;

    // merge the RS split winners (lane s holds split s)
    float v = -1e30f;
    int   c = 0;
    if (lane < RS) { v = pval[(size_t)lane * N + j]; c = pcode[(size_t)lane * N + j]; }
#pragma unroll
    for (int m = 1; m <= 8; m <<= 1) {
        const float ov = __shfl_xor(v, m, 64);
        const int   oc = __shfl_xor(c, m, 64);
        if (ov > v || (ov == v && oc < c)) { v = ov; c = oc; }
    }
    c = __shfl(c, 0, 64);

    const float2 qv = *(const float2*)(q + (size_t)j * D + lane * 2);
    const float2 tv = *(const float2*)(t + (size_t)j * D + lane * 2);
    float qq = qv.x * qv.x + qv.y * qv.y;
    float tt = tv.x * tv.x + tv.y * tv.y;
    float qt = qv.x * tv.x + qv.y * tv.y;
    float ww[4], wt[4], qw[4];
#pragma unroll
    for (int r = 0; r < 4; ++r) {
        const float2 wv = *(const float2*)(t + (size_t)(c + r) * D + lane * 2);
        ww[r] = wv.x * wv.x + wv.y * wv.y;
        wt[r] = wv.x * tv.x + wv.y * tv.y;
        qw[r] = wv.x * qv.x + wv.y * qv.y;
    }
#pragma unroll
    for (int m = 1; m <= 32; m <<= 1) {
        qq += __shfl_xor(qq, m, 64);
        tt += __shfl_xor(tt, m, 64);
        qt += __shfl_xor(qt, m, 64);
#pragma unroll
        for (int r = 0; r < 4; ++r) {
            ww[r] += __shfl_xor(ww[r], m, 64);
            wt[r] += __shfl_xor(wt[r], m, 64);
            qw[r] += __shfl_xor(qw[r], m, 64);
        }
    }
    const float pos = qt * rsqrtf(qq * tt);
    float best = -1e30f, neg = 0.f;
#pragma unroll
    for (int r = 0; r < 4; ++r) {
        float cr = wt[r] * rsqrtf(ww[r] * tt);
        if (c + r == j) cr -= 1.0f;              // diag candidate, matches sim - eye
        if (cr > best) { best = cr; neg = qw[r] * rsqrtf(qq * ww[r]); }
    }
    const float l = fmaxf(0.f, 1.0f - pos + neg);

    __shared__ float ls[4];
    if (lane == 0) ls[threadIdx.x >> 6] = l;
    __syncthreads();
    if (threadIdx.x == 0) bsum[blockIdx.x] = ls[0] + ls[1] + ls[2] + ls[3];
}

// ---------------- Kernel D: deterministic final mean ----------------
__global__ __launch_bounds__(256) void kfinal(const float* __restrict__ bsum,
                                              float* __restrict__ out) {
    float sum = 0.f;
    for (int i = threadIdx.x; i < N / 4; i += 256) sum += bsum[i];
#pragma unroll
    for (int m = 1; m <= 32; m <<= 1) sum += __shfl_xor(sum, m, 64);
    __shared__ float ws2[4];
    if ((threadIdx.x & 63) == 0) ws2[threadIdx.x >> 6] = sum;
    __syncthreads();
    if (threadIdx.x == 0) out[0] = (ws2[0] + ws2[1] + ws2[2] + ws2[3]) * (1.0f / N);
}

extern "C" void kernel_launch(void* const* d_in, const int* in_sizes, int n_in,
                              void* d_out, int out_size, void* d_ws, size_t ws_size,
                              hipStream_t stream) {
    const float* q = (const float*)d_in[0];
    const float* t = (const float*)d_in[1];
    char* ws = (char*)d_ws;

    __hip_bfloat16* bn = (__hip_bfloat16*)ws;                          // 4 MB (must stay first)
    float* pval = (float*)(ws + (size_t)N * D * 2);                    // 1 MB (also overshoot pad)
    int*   pcode = (int*)(ws + (size_t)N * D * 2 + (size_t)RS * N * 4);// 1 MB
    float* bsum = (float*)(ws + (size_t)N * D * 2 + (size_t)2 * RS * N * 4); // 16 KB

    knorm<<<dim3(N / 4), dim3(256), 0, stream>>>(t, bn);
    kargmax<<<dim3(CTILES * RS), dim3(1024), 0, stream>>>(bn, pval, pcode);
    kloss<<<dim3(N / 4), dim3(256), 0, stream>>>(q, t, pval, pcode, bsum);
    kfinal<<<dim3(1), dim3(256), 0, stream>>>(bsum, (float*)d_out);
}

// Round 9
// 102.407 us; speedup vs baseline: 2.6079x; 2.4278x over previous
//
#include <hip/hip_runtime.h>
#include <hip/hip_bf16.h>

#define N 16384
#define D 128
#define RS 16                        // row splits
#define CT 32                        // col tiles (N / 512)
#define ROWS_PER_SPLIT (N / RS)      // 1024
#define ITERS (ROWS_PER_SPLIT / 16)  // 64

typedef __attribute__((ext_vector_type(8))) short bf16x8;
typedef __attribute__((ext_vector_type(4))) float f32x4;

// ---------------- Kernel A: normalize targets -> bf16 bn ----------------
__global__ __launch_bounds__(256) void knorm(const float* __restrict__ t,
                                             __hip_bfloat16* __restrict__ bn) {
    const int row  = blockIdx.x * 4 + (threadIdx.x >> 6);
    const int lane = threadIdx.x & 63;
    const float2 v = *(const float2*)(t + (size_t)row * D + lane * 2);
    float ss = v.x * v.x + v.y * v.y;
#pragma unroll
    for (int m = 1; m <= 32; m <<= 1) ss += __shfl_xor(ss, m, 64);
    const float inv = rsqrtf(ss);
    __hip_bfloat162 o;
    o.x = __float2bfloat16(v.x * inv);
    o.y = __float2bfloat16(v.y * inv);
    *(__hip_bfloat162*)(bn + (size_t)row * D + lane * 2) = o;
}

// ---------------- Kernel B: fused bn @ bn^T + per-column group-argmax ----------------
// R2 structure (empirically best): 512 blocks x 4 waves, no LDS, no barriers.
// Wave w: cols [ct*512 + w*128, +128) persistent in fb[8][4] (AGPR-backed);
// rows [s*1024,(s+1)*1024) streamed via double-buffered register loads, all 4
// waves read identical A addresses -> L1 dedup. NEW decode: XCD x holds exactly
// 2 A-streams (512 KB, L2-resident) and both co-resident blocks per CU share one
// stream (8-wave L1 dedup): s = (b&7)*2 + ((b>>3)&1), ct = b>>4.
// Argmax packs (group max, 8-bit group id) into one float (low mantissa byte).
__global__ __launch_bounds__(256, 2) void kargmax(const __hip_bfloat16* __restrict__ bn,
                                                  float* __restrict__ pval,
                                                  int* __restrict__ pcode) {
    const int tid  = threadIdx.x;
    const int lane = tid & 63;
    const int w    = tid >> 6;
    const int b    = blockIdx.x;
    const int s    = (b & 7) * 2 + ((b >> 3) & 1);   // 2 splits per XCD
    const int ct   = b >> 4;                          // 0..31
    const int j0w  = ct * 512 + w * 128;
    const int rbase = s * ROWS_PER_SPLIT;

    const int lr = lane & 15;
    const int lk = lane >> 4;

    // persistent B fragments: 128 cols x 128 K (128 regs, AGPR-backed)
    bf16x8 fb[8][4];
#pragma unroll
    for (int cs = 0; cs < 8; ++cs)
#pragma unroll
        for (int ks = 0; ks < 4; ++ks)
            fb[cs][ks] = *(const bf16x8*)(bn + (size_t)(j0w + cs * 16 + lr) * D + ks * 32 + lk * 8);

    const char* aptr = (const char*)bn + (size_t)(rbase + lr) * 256 + lk * 16;

    float mv[8];
#pragma unroll
    for (int cs = 0; cs < 8; ++cs) mv[cs] = -1e30f;
    unsigned gidxv = (unsigned)lk;      // group id = it*4 + lk (0..255)

    const f32x4 z4 = {0.f, 0.f, 0.f, 0.f};
    bf16x8 faA[4], faB[4];

#define LOADF(buf, itv) do {                                        \
    const char* p_ = aptr + (size_t)(itv) * 4096;                   \
    buf[0] = *(const bf16x8*)(p_);                                  \
    buf[1] = *(const bf16x8*)(p_ + 64);                             \
    buf[2] = *(const bf16x8*)(p_ + 128);                            \
    buf[3] = *(const bf16x8*)(p_ + 192); } while (0)

#define COMPUTEF(buf, itv) do {                                                             \
    f32x4 acc[8];                                                                           \
    __builtin_amdgcn_s_setprio(1);                                                          \
    _Pragma("unroll")                                                                       \
    for (int cs = 0; cs < 8; ++cs) {                                                        \
        acc[cs] = __builtin_amdgcn_mfma_f32_16x16x32_bf16(buf[0], fb[cs][0], z4, 0, 0, 0);  \
        _Pragma("unroll")                                                                   \
        for (int ks = 1; ks < 4; ++ks)                                                      \
            acc[cs] = __builtin_amdgcn_mfma_f32_16x16x32_bf16(buf[ks], fb[cs][ks], acc[cs], 0, 0, 0); \
    }                                                                                       \
    __builtin_amdgcn_s_setprio(0);                                                          \
    const int r0_ = rbase + (itv) * 16;                                                     \
    if ((unsigned)(r0_ - j0w) < 128u) {                                                     \
        _Pragma("unroll")                                                                   \
        for (int cs = 0; cs < 8; ++cs)                                                      \
            if (r0_ == j0w + cs * 16) {                                                     \
                _Pragma("unroll")                                                           \
                for (int r = 0; r < 4; ++r)                                                 \
                    acc[cs][r] = (lk * 4 + r == lr) ? acc[cs][r] - 1.0f : acc[cs][r];       \
            }                                                                               \
    }                                                                                       \
    _Pragma("unroll")                                                                       \
    for (int cs = 0; cs < 8; ++cs) {                                                        \
        const float g_ = fmaxf(fmaxf(fmaxf(acc[cs][0], acc[cs][1]), acc[cs][2]), acc[cs][3]); \
        const unsigned gb_ = (__float_as_uint(g_) & 0xFFFFFF00u) | gidxv;                   \
        mv[cs] = fmaxf(mv[cs], __uint_as_float(gb_));                                       \
    }                                                                                       \
    gidxv += 4u; } while (0)

    LOADF(faA, 0);
    for (int it2 = 0; it2 < ITERS; it2 += 2) {
        LOADF(faB, it2 + 1);
        COMPUTEF(faA, it2);
        LOADF(faA, it2 + 2);   // final overshoot reads into pval region — allocated, unused
        COMPUTEF(faB, it2 + 1);
    }
#undef LOADF
#undef COMPUTEF

    // reduce across the 4 lk groups (packed fmax — group id rides in low byte)
#pragma unroll
    for (int cs = 0; cs < 8; ++cs) {
        float v = mv[cs];
        v = fmaxf(v, __shfl_xor(v, 16, 64));
        v = fmaxf(v, __shfl_xor(v, 32, 64));
        if (lane < 16) {
            pval[(size_t)s * N + j0w + cs * 16 + lr]  = v;
            pcode[(size_t)s * N + j0w + cs * 16 + lr] =
                rbase + (int)(__float_as_uint(v) & 255u) * 4;
        }
    }
}

// ---------------- Kernel C: merge splits, re-rank 4 candidates in fp32, hinge ----------------
__global__ __launch_bounds__(256) void kloss(const float* __restrict__ q,
                                             const float* __restrict__ t,
                                             const float* __restrict__ pval,
                                             const int* __restrict__ pcode,
                                             float* __restrict__ bsum) {
    const int j    = blockIdx.x * 4 + (threadIdx.x >> 6);
    const int lane = threadIdx.x & 63;

    // merge the RS split winners (lane s holds split s)
    float v = -1e30f;
    int   c = 0;
    if (lane < RS) { v = pval[(size_t)lane * N + j]; c = pcode[(size_t)lane * N + j]; }
#pragma unroll
    for (int m = 1; m <= 8; m <<= 1) {
        const float ov = __shfl_xor(v, m, 64);
        const int   oc = __shfl_xor(c, m, 64);
        if (ov > v || (ov == v && oc < c)) { v = ov; c = oc; }
    }
    c = __shfl(c, 0, 64);

    const float2 qv = *(const float2*)(q + (size_t)j * D + lane * 2);
    const float2 tv = *(const float2*)(t + (size_t)j * D + lane * 2);
    float qq = qv.x * qv.x + qv.y * qv.y;
    float tt = tv.x * tv.x + tv.y * tv.y;
    float qt = qv.x * tv.x + qv.y * tv.y;
    float ww[4], wt[4], qw[4];
#pragma unroll
    for (int r = 0; r < 4; ++r) {
        const float2 wv = *(const float2*)(t + (size_t)(c + r) * D + lane * 2);
        ww[r] = wv.x * wv.x + wv.y * wv.y;
        wt[r] = wv.x * tv.x + wv.y * tv.y;
        qw[r] = wv.x * qv.x + wv.y * qv.y;
    }
#pragma unroll
    for (int m = 1; m <= 32; m <<= 1) {
        qq += __shfl_xor(qq, m, 64);
        tt += __shfl_xor(tt, m, 64);
        qt += __shfl_xor(qt, m, 64);
#pragma unroll
        for (int r = 0; r < 4; ++r) {
            ww[r] += __shfl_xor(ww[r], m, 64);
            wt[r] += __shfl_xor(wt[r], m, 64);
            qw[r] += __shfl_xor(qw[r], m, 64);
        }
    }
    const float pos = qt * rsqrtf(qq * tt);
    float best = -1e30f, neg = 0.f;
#pragma unroll
    for (int r = 0; r < 4; ++r) {
        float cr = wt[r] * rsqrtf(ww[r] * tt);
        if (c + r == j) cr -= 1.0f;              // diag candidate, matches sim - eye
        if (cr > best) { best = cr; neg = qw[r] * rsqrtf(qq * ww[r]); }
    }
    const float l = fmaxf(0.f, 1.0f - pos + neg);

    __shared__ float ls[4];
    if (lane == 0) ls[threadIdx.x >> 6] = l;
    __syncthreads();
    if (threadIdx.x == 0) bsum[blockIdx.x] = ls[0] + ls[1] + ls[2] + ls[3];
}

// ---------------- Kernel D: deterministic final mean ----------------
__global__ __launch_bounds__(256) void kfinal(const float* __restrict__ bsum,
                                              float* __restrict__ out) {
    float sum = 0.f;
    for (int i = threadIdx.x; i < N / 4; i += 256) sum += bsum[i];
#pragma unroll
    for (int m = 1; m <= 32; m <<= 1) sum += __shfl_xor(sum, m, 64);
    __shared__ float ws2[4];
    if ((threadIdx.x & 63) == 0) ws2[threadIdx.x >> 6] = sum;
    __syncthreads();
    if (threadIdx.x == 0) out[0] = (ws2[0] + ws2[1] + ws2[2] + ws2[3]) * (1.0f / N);
}

extern "C" void kernel_launch(void* const* d_in, const int* in_sizes, int n_in,
                              void* d_out, int out_size, void* d_ws, size_t ws_size,
                              hipStream_t stream) {
    const float* q = (const float*)d_in[0];
    const float* t = (const float*)d_in[1];
    char* ws = (char*)d_ws;

    __hip_bfloat16* bn = (__hip_bfloat16*)ws;                          // 4 MB (must stay first)
    float* pval = (float*)(ws + (size_t)N * D * 2);                    // 1 MB (also overshoot pad)
    int*   pcode = (int*)(ws + (size_t)N * D * 2 + (size_t)RS * N * 4);// 1 MB
    float* bsum = (float*)(ws + (size_t)N * D * 2 + (size_t)2 * RS * N * 4); // 16 KB

    knorm<<<dim3(N / 4), dim3(256), 0, stream>>>(t, bn);
    kargmax<<<dim3(CT * RS), dim3(256), 0, stream>>>(bn, pval, pcode);
    kloss<<<dim3(N / 4), dim3(256), 0, stream>>>(q, t, pval, pcode, bsum);
    kfinal<<<dim3(1), dim3(256), 0, stream>>>(bsum, (float*)d_out);
}

// Round 10
// 78.376 us; speedup vs baseline: 3.4074x; 1.3066x over previous
//
#include <hip/hip_runtime.h>
#include <hip/hip_bf16.h>

#define N 16384
#define D 128
#define RS 16                        // row splits
#define CT 32                        // col tiles (N / 512)
#define ROWS_PER_SPLIT (N / RS)      // 1024
#define ITERS (ROWS_PER_SPLIT / 16)  // 64

typedef __attribute__((ext_vector_type(4))) float f32x4;
typedef long long i64;
typedef __attribute__((ext_vector_type(2))) long long i64x2;

// ---------------- Kernel A: normalize targets -> fp8 e4m3, fragment-permuted ----------------
// byte for (row, k) stored at row*128 + ((k>>3)&3)*32 + (k>>5)*8 + (k&7):
// each MFMA lane's (row, ks=0..3) fragment bytes become 32 contiguous bytes.
__global__ __launch_bounds__(256) void knorm(const float* __restrict__ t,
                                             unsigned char* __restrict__ bnq) {
    const int row  = blockIdx.x * 4 + (threadIdx.x >> 6);
    const int lane = threadIdx.x & 63;
    const float2 v = *(const float2*)(t + (size_t)row * D + lane * 2);
    float ss = v.x * v.x + v.y * v.y;
#pragma unroll
    for (int m = 1; m <= 32; m <<= 1) ss += __shfl_xor(ss, m, 64);
    const float inv = rsqrtf(ss);
    const int k   = lane * 2;
    const int off = ((k >> 3) & 3) * 32 + (k >> 5) * 8 + (k & 7);
    const unsigned bits =
        (unsigned)__builtin_amdgcn_cvt_pk_fp8_f32(v.x * inv, v.y * inv, 0, false);
    *(unsigned short*)(bnq + (size_t)row * 128 + off) = (unsigned short)(bits & 0xFFFFu);
}

// ---------------- Kernel B: fused fp8 bn @ bn^T + per-column group-argmax ----------------
// R2/R9 geometry (512 blocks x 4 waves, no LDS, no barriers), fp8 operands:
// fb[8][4] = 64 regs, A-frames 8 regs each -> QUAD-buffered prefetch (depth 4,
// ~5000 cyc cover). XCD decode: s=(b&7)*2+((b>>3)&1), ct=b>>4 (L2-resident streams).
__global__ __launch_bounds__(256, 2) void kargmax(const unsigned char* __restrict__ bnq,
                                                  float* __restrict__ pval,
                                                  int* __restrict__ pcode) {
    const int tid  = threadIdx.x;
    const int lane = tid & 63;
    const int w    = tid >> 6;
    const int b    = blockIdx.x;
    const int s    = (b & 7) * 2 + ((b >> 3) & 1);   // 2 splits per XCD
    const int ct   = b >> 4;                          // 0..31
    const int j0w  = ct * 512 + w * 128;
    const int rbase = s * ROWS_PER_SPLIT;

    const int lr = lane & 15;
    const int lk = lane >> 4;

    // persistent B fragments: 128 cols x 128 K, fp8 (64 VGPRs)
    i64 fb[8][4];
#pragma unroll
    for (int cs = 0; cs < 8; ++cs)
#pragma unroll
        for (int ks = 0; ks < 4; ++ks)
            fb[cs][ks] = *(const i64*)(bnq + (size_t)(j0w + cs * 16 + lr) * 128 +
                                       lk * 32 + ks * 8);

    const unsigned char* aptr = bnq + (size_t)(rbase + lr) * 128 + lk * 32;

    float mv[8];
#pragma unroll
    for (int cs = 0; cs < 8; ++cs) mv[cs] = -1e30f;
    unsigned gidxv = (unsigned)lk;      // group id = it*4 + lk (0..255)

    const f32x4 z4 = {0.f, 0.f, 0.f, 0.f};
    i64x2 fA[2], fB[2], fC[2], fD[2];

#define LOADF(buf, itv) do {                                  \
    const unsigned char* p_ = aptr + (size_t)(itv) * 2048;    \
    buf[0] = *(const i64x2*)(p_);                             \
    buf[1] = *(const i64x2*)(p_ + 16); } while (0)

#define COMPUTEF(buf, itv) do {                                                             \
    f32x4 acc[8];                                                                           \
    __builtin_amdgcn_s_setprio(1);                                                          \
    _Pragma("unroll")                                                                       \
    for (int cs = 0; cs < 8; ++cs) {                                                        \
        acc[cs] = __builtin_amdgcn_mfma_f32_16x16x32_fp8_fp8(buf[0][0], fb[cs][0], z4, 0, 0, 0); \
        acc[cs] = __builtin_amdgcn_mfma_f32_16x16x32_fp8_fp8(buf[0][1], fb[cs][1], acc[cs], 0, 0, 0); \
        acc[cs] = __builtin_amdgcn_mfma_f32_16x16x32_fp8_fp8(buf[1][0], fb[cs][2], acc[cs], 0, 0, 0); \
        acc[cs] = __builtin_amdgcn_mfma_f32_16x16x32_fp8_fp8(buf[1][1], fb[cs][3], acc[cs], 0, 0, 0); \
    }                                                                                       \
    __builtin_amdgcn_s_setprio(0);                                                          \
    const int r0_ = rbase + (itv) * 16;                                                     \
    if ((unsigned)(r0_ - j0w) < 128u) {                                                     \
        _Pragma("unroll")                                                                   \
        for (int cs = 0; cs < 8; ++cs)                                                      \
            if (r0_ == j0w + cs * 16) {                                                     \
                _Pragma("unroll")                                                           \
                for (int r = 0; r < 4; ++r)                                                 \
                    acc[cs][r] = (lk * 4 + r == lr) ? acc[cs][r] - 1.0f : acc[cs][r];       \
            }                                                                               \
    }                                                                                       \
    _Pragma("unroll")                                                                       \
    for (int cs = 0; cs < 8; ++cs) {                                                        \
        const float g_ = fmaxf(fmaxf(fmaxf(acc[cs][0], acc[cs][1]), acc[cs][2]), acc[cs][3]); \
        const unsigned gb_ = (__float_as_uint(g_) & 0xFFFFFF00u) | gidxv;                   \
        mv[cs] = fmaxf(mv[cs], __uint_as_float(gb_));                                       \
    }                                                                                       \
    gidxv += 4u; } while (0)

    LOADF(fA, 0);
    LOADF(fB, 1);
    LOADF(fC, 2);
    LOADF(fD, 3);
    for (int q4 = 0; q4 < ITERS; q4 += 4) {
        COMPUTEF(fA, q4);     LOADF(fA, q4 + 4);   // trailing overshoot (~8 KB)
        COMPUTEF(fB, q4 + 1); LOADF(fB, q4 + 5);   // lands in pval pad — allocated, unused
        COMPUTEF(fC, q4 + 2); LOADF(fC, q4 + 6);
        COMPUTEF(fD, q4 + 3); LOADF(fD, q4 + 7);
    }
#undef LOADF
#undef COMPUTEF

    // reduce across the 4 lk groups (packed fmax — group id rides in low byte)
#pragma unroll
    for (int cs = 0; cs < 8; ++cs) {
        float v = mv[cs];
        v = fmaxf(v, __shfl_xor(v, 16, 64));
        v = fmaxf(v, __shfl_xor(v, 32, 64));
        if (lane < 16) {
            pval[(size_t)s * N + j0w + cs * 16 + lr]  = v;
            pcode[(size_t)s * N + j0w + cs * 16 + lr] =
                rbase + (int)(__float_as_uint(v) & 255u) * 4;
        }
    }
}

// ---------------- Kernel C: merge splits, re-rank 4 candidates in fp32, hinge ----------------
__global__ __launch_bounds__(256) void kloss(const float* __restrict__ q,
                                             const float* __restrict__ t,
                                             const float* __restrict__ pval,
                                             const int* __restrict__ pcode,
                                             float* __restrict__ bsum) {
    const int j    = blockIdx.x * 4 + (threadIdx.x >> 6);
    const int lane = threadIdx.x & 63;

    // merge the RS split winners (lane s holds split s)
    float v = -1e30f;
    int   c = 0;
    if (lane < RS) { v = pval[(size_t)lane * N + j]; c = pcode[(size_t)lane * N + j]; }
#pragma unroll
    for (int m = 1; m <= 8; m <<= 1) {
        const float ov = __shfl_xor(v, m, 64);
        const int   oc = __shfl_xor(c, m, 64);
        if (ov > v || (ov == v && oc < c)) { v = ov; c = oc; }
    }
    c = __shfl(c, 0, 64);

    const float2 qv = *(const float2*)(q + (size_t)j * D + lane * 2);
    const float2 tv = *(const float2*)(t + (size_t)j * D + lane * 2);
    float qq = qv.x * qv.x + qv.y * qv.y;
    float tt = tv.x * tv.x + tv.y * tv.y;
    float qt = qv.x * tv.x + qv.y * tv.y;
    float ww[4], wt[4], qw[4];
#pragma unroll
    for (int r = 0; r < 4; ++r) {
        const float2 wv = *(const float2*)(t + (size_t)(c + r) * D + lane * 2);
        ww[r] = wv.x * wv.x + wv.y * wv.y;
        wt[r] = wv.x * tv.x + wv.y * tv.y;
        qw[r] = wv.x * qv.x + wv.y * qv.y;
    }
#pragma unroll
    for (int m = 1; m <= 32; m <<= 1) {
        qq += __shfl_xor(qq, m, 64);
        tt += __shfl_xor(tt, m, 64);
        qt += __shfl_xor(qt, m, 64);
#pragma unroll
        for (int r = 0; r < 4; ++r) {
            ww[r] += __shfl_xor(ww[r], m, 64);
            wt[r] += __shfl_xor(wt[r], m, 64);
            qw[r] += __shfl_xor(qw[r], m, 64);
        }
    }
    const float pos = qt * rsqrtf(qq * tt);
    float best = -1e30f, neg = 0.f;
#pragma unroll
    for (int r = 0; r < 4; ++r) {
        float cr = wt[r] * rsqrtf(ww[r] * tt);
        if (c + r == j) cr -= 1.0f;              // diag candidate, matches sim - eye
        if (cr > best) { best = cr; neg = qw[r] * rsqrtf(qq * ww[r]); }
    }
    const float l = fmaxf(0.f, 1.0f - pos + neg);

    __shared__ float ls[4];
    if (lane == 0) ls[threadIdx.x >> 6] = l;
    __syncthreads();
    if (threadIdx.x == 0) bsum[blockIdx.x] = ls[0] + ls[1] + ls[2] + ls[3];
}

// ---------------- Kernel D: deterministic final mean ----------------
__global__ __launch_bounds__(256) void kfinal(const float* __restrict__ bsum,
                                              float* __restrict__ out) {
    float sum = 0.f;
    for (int i = threadIdx.x; i < N / 4; i += 256) sum += bsum[i];
#pragma unroll
    for (int m = 1; m <= 32; m <<= 1) sum += __shfl_xor(sum, m, 64);
    __shared__ float ws2[4];
    if ((threadIdx.x & 63) == 0) ws2[threadIdx.x >> 6] = sum;
    __syncthreads();
    if (threadIdx.x == 0) out[0] = (ws2[0] + ws2[1] + ws2[2] + ws2[3]) * (1.0f / N);
}

extern "C" void kernel_launch(void* const* d_in, const int* in_sizes, int n_in,
                              void* d_out, int out_size, void* d_ws, size_t ws_size,
                              hipStream_t stream) {
    const float* q = (const float*)d_in[0];
    const float* t = (const float*)d_in[1];
    char* ws = (char*)d_ws;

    unsigned char* bnq = (unsigned char*)ws;                           // 2 MB (must stay first)
    float* pval = (float*)(ws + (size_t)N * 128);                      // 1 MB (also overshoot pad)
    int*   pcode = (int*)(ws + (size_t)N * 128 + (size_t)RS * N * 4);  // 1 MB
    float* bsum = (float*)(ws + (size_t)N * 128 + (size_t)2 * RS * N * 4); // 16 KB

    knorm<<<dim3(N / 4), dim3(256), 0, stream>>>(t, bnq);
    kargmax<<<dim3(CT * RS), dim3(256), 0, stream>>>(bnq, pval, pcode);
    kloss<<<dim3(N / 4), dim3(256), 0, stream>>>(q, t, pval, pcode, bsum);
    kfinal<<<dim3(1), dim3(256), 0, stream>>>(bsum, (float*)d_out);
}